// Round 3
// baseline (183.690 us; speedup 1.0000x reference)
//
#include <hip/hip_runtime.h>
#include <hip/hip_bf16.h>

// GraphConv: out = relu( segment_sum(x[src], dst) @ W_rel^T + b_rel + x @ W_root^T )
// N = 50000, F = 128, E = 800000.
//
// R14: attack agg_gemm's two serial sinks (profiled 49.6us, latency-bound:
// VALUBusy 26%, HBM 28%, occ 50%):
//   - flattened bin staging: 8 mostly-idle partition rounds (cnt~64/256 active)
//     -> flat index over partOff[] prefix, ~2 full-width rounds for bin-read,
//     LDS histogram, and LDS scatter (serial critical path ~4x shorter).
//   - paired-dst gather: two dsts per wave (dA=wave+8j, dB=dA+4) with merged
//     8-row quantum -> 4 independent 1KB loads continuously in flight, and the
//     two shfl-reduce chains overlap (mean degree 16 made per-dst reduce the
//     serialization point).
// prep_bin unchanged (all its dispatches profiled < agg).
// Fallback (tiny ws): fp32 atomic scatter + fused fp32 GEMM.

#define F 128
#define NPB 32              // nodes per bucket
#define NPARTS 8            // write partitions (blockIdx%8 ~ XCD heuristic)
#define CAP 128             // slots per (part,bucket); mean 64 -> +8 sigma
#define CAPB 768            // LDS edge slots per bucket; mean 512 -> +11 sigma
#define AST 68              // A-tile row stride in uints

typedef __bf16 bf16x8 __attribute__((ext_vector_type(8)));
typedef float f32x4 __attribute__((ext_vector_type(4)));

__device__ inline unsigned f32_to_bf16_rne(float f) {
  unsigned u = __float_as_uint(f);
  unsigned r = u + 0x7fffu + ((u >> 16) & 1u);
  return r >> 16;
}
__device__ inline unsigned pack2(float2 v) {
  return f32_to_bf16_rne(v.x) | (f32_to_bf16_rne(v.y) << 16);
}
__device__ inline unsigned pack2f(float a, float b) {
  return f32_to_bf16_rne(a) | (f32_to_bf16_rne(b) << 16);
}
__device__ inline void upk4(uint4 v, float* a) {
  a[0] += __uint_as_float(v.x << 16);
  a[1] += __uint_as_float(v.x & 0xffff0000u);
  a[2] += __uint_as_float(v.y << 16);
  a[3] += __uint_as_float(v.y & 0xffff0000u);
  a[4] += __uint_as_float(v.z << 16);
  a[5] += __uint_as_float(v.z & 0xffff0000u);
  a[6] += __uint_as_float(v.w << 16);
  a[7] += __uint_as_float(v.w & 0xffff0000u);
}

// drain the remaining (<16, then <8) rows of one dst's edge run
__device__ inline void gather_drain(const uint4* __restrict__ xb4,
                                    const unsigned short* __restrict__ eLds,
                                    int e, int end, int grp, int l16,
                                    float* a8) {
  for (; e + 16 <= end; e += 16) {
    int s0 = eLds[e + grp];
    int s1 = eLds[e + 4 + grp];
    int s2 = eLds[e + 8 + grp];
    int s3 = eLds[e + 12 + grp];
    uint4 v0 = xb4[(size_t)s0 * 16 + l16];
    uint4 v1 = xb4[(size_t)s1 * 16 + l16];
    uint4 v2 = xb4[(size_t)s2 * 16 + l16];
    uint4 v3 = xb4[(size_t)s3 * 16 + l16];
    upk4(v0, a8);
    upk4(v1, a8);
    upk4(v2, a8);
    upk4(v3, a8);
  }
  if (e + 8 <= end) {
    int s0 = eLds[e + grp];
    int s1 = eLds[e + 4 + grp];
    uint4 v0 = xb4[(size_t)s0 * 16 + l16];
    uint4 v1 = xb4[(size_t)s1 * 16 + l16];
    upk4(v0, a8);
    upk4(v1, a8);
    e += 8;
  }
  if (e < end) {
    int i0 = e + grp;
    int i1 = e + 4 + grp;
    if (i0 < end) {
      uint4 v0 = xb4[(size_t)eLds[i0] * 16 + l16];
      upk4(v0, a8);
    }
    if (i1 < end) {
      uint4 v1 = xb4[(size_t)eLds[i1] * 16 + l16];
      upk4(v1, a8);
    }
  }
}

// ---------------------------------------------------------------------------
// Dispatch 1: bf16 converts + edge binning (binCursor pre-zeroed by memset)
// ---------------------------------------------------------------------------
__global__ __launch_bounds__(256) void prep_bin2_kernel(
    const float4* __restrict__ x, const float2* __restrict__ w0,
    const float2* __restrict__ w1, const int* __restrict__ ei,
    uint2* __restrict__ xb2, unsigned* __restrict__ wb,
    int* __restrict__ binCursor, unsigned* __restrict__ bin,
    int E, int NB, int n4x, int n2w) {
  const int tid0 = blockIdx.x * 256 + threadIdx.x;
  const int stride = gridDim.x * 256;

  // edges first: atomics have the longest latency chains, start them early
  const int part = blockIdx.x & (NPARTS - 1);
  for (int e = tid0; e < E; e += stride) {
    unsigned src = (unsigned)ei[e];
    unsigned dst = (unsigned)ei[E + e];
    int cell = part * NB + (int)(dst >> 5);
    int slot = atomicAdd(&binCursor[cell], 1);
    if (slot < CAP) bin[(size_t)cell * CAP + slot] = (dst << 16) | src;
  }
  // x convert: float4 -> 2x packed bf16 (16B in / 8B out per iter)
  for (int i = tid0; i < n4x; i += stride) {
    float4 v = x[i];
    xb2[i] = make_uint2(pack2f(v.x, v.y), pack2f(v.z, v.w));
  }
  // weights
  for (int i = tid0; i < 2 * n2w; i += stride)
    wb[i] = (i < n2w) ? pack2(w0[i]) : pack2(w1[i - n2w]);
}

// ---------------------------------------------------------------------------
// Dispatch 2: flattened LDS sort + paired-dst wide gather + dual MFMA GEMM
// ---------------------------------------------------------------------------
__global__ __launch_bounds__(256) void agg_gemm3_kernel(
    const unsigned* __restrict__ xb, const unsigned* __restrict__ bin,
    const int* __restrict__ binCursor, const __bf16* __restrict__ wb,
    const float* __restrict__ brel, float* __restrict__ out, int N, int NB) {
  __shared__ int cntS[NPB];
  __shared__ int offS[NPB];
  __shared__ int curS[NPB];
  __shared__ unsigned short eLds[CAPB];
  __shared__ unsigned aLds[NPB * AST];

  const int b = blockIdx.x;
  const int t = threadIdx.x;
  if (t < NPB) cntS[t] = 0;
  __syncthreads();

  // ---- flattened bin staging: cursors are block-uniform -> scalar loads ----
  int partOff[NPARTS + 1];
  partOff[0] = 0;
#pragma unroll
  for (int p = 0; p < NPARTS; ++p) {
    int c = min(binCursor[p * NB + b], CAP);
    partOff[p + 1] = partOff[p] + c;
  }
  const int total = partOff[NPARTS];  // <= NPARTS*CAP = 1024

  unsigned key[4];
#pragma unroll
  for (int r = 0; r < 4; ++r) {
    int i = t + r * 256;
    unsigned k = 0u;
    if (i < total) {
      int p = 0;
#pragma unroll
      for (int q = 1; q < NPARTS; ++q) p += (i >= partOff[q]);
      int slot = i - partOff[p];
      k = bin[(size_t)(p * NB + b) * CAP + slot];
    }
    key[r] = k;
  }
#pragma unroll
  for (int r = 0; r < 4; ++r) {
    if (t + r * 256 < total) atomicAdd(&cntS[(key[r] >> 16) & (NPB - 1)], 1);
  }
  __syncthreads();

  if (t < 64) {
    int v = (t < NPB) ? cntS[t] : 0;
    int incl = v;
#pragma unroll
    for (int off = 1; off < NPB; off <<= 1) {
      int u = __shfl_up(incl, off);
      if (t >= off) incl += u;
    }
    if (t < NPB) {
      offS[t] = incl - v;
      curS[t] = incl - v;
    }
  }
  __syncthreads();

#pragma unroll
  for (int r = 0; r < 4; ++r) {
    if (t + r * 256 < total) {
      int d = (key[r] >> 16) & (NPB - 1);
      int pos = atomicAdd(&curS[d], 1);
      if (pos < CAPB) eLds[pos] = (unsigned short)(key[r] & 0xffffu);
    }
  }
  __syncthreads();

  // ---- paired-dst wide gather: 16 lanes/row x dwordx4; two dsts per wave ----
  const int wave = t >> 6;
  const int lane = t & 63;
  const int grp = lane >> 4;
  const int l16 = lane & 15;
  const uint4* __restrict__ xb4 = (const uint4*)xb;
  const int nodeBase = b * NPB;

#pragma unroll
  for (int j = 0; j < 4; ++j) {
    const int dA = wave + 8 * j;
    const int dB = dA + 4;
    float a8[8] = {0.f, 0.f, 0.f, 0.f, 0.f, 0.f, 0.f, 0.f};
    float b8[8] = {0.f, 0.f, 0.f, 0.f, 0.f, 0.f, 0.f, 0.f};
    int eA = min(offS[dA], CAPB);
    int endA = min(offS[dA] + cntS[dA], CAPB);
    int eB = min(offS[dB], CAPB);
    int endB = min(offS[dB] + cntS[dB], CAPB);
    // merged main loop: 4 independent 1KB loads in flight across both dsts
    while (eA + 8 <= endA && eB + 8 <= endB) {
      int sA0 = eLds[eA + grp];
      int sA1 = eLds[eA + 4 + grp];
      int sB0 = eLds[eB + grp];
      int sB1 = eLds[eB + 4 + grp];
      uint4 vA0 = xb4[(size_t)sA0 * 16 + l16];
      uint4 vA1 = xb4[(size_t)sA1 * 16 + l16];
      uint4 vB0 = xb4[(size_t)sB0 * 16 + l16];
      uint4 vB1 = xb4[(size_t)sB1 * 16 + l16];
      upk4(vA0, a8);
      upk4(vA1, a8);
      upk4(vB0, b8);
      upk4(vB1, b8);
      eA += 8;
      eB += 8;
    }
    gather_drain(xb4, eLds, eA, endA, grp, l16, a8);
    gather_drain(xb4, eLds, eB, endB, grp, l16, b8);
    // independent reduce chains -> overlap
#pragma unroll
    for (int q = 0; q < 8; ++q) {
      a8[q] += __shfl_xor(a8[q], 16);
      b8[q] += __shfl_xor(b8[q], 16);
      a8[q] += __shfl_xor(a8[q], 32);
      b8[q] += __shfl_xor(b8[q], 32);
    }
    if (grp == 0) {
      uint4 pkA, pkB;
      pkA.x = pack2f(a8[0], a8[1]);
      pkA.y = pack2f(a8[2], a8[3]);
      pkA.z = pack2f(a8[4], a8[5]);
      pkA.w = pack2f(a8[6], a8[7]);
      pkB.x = pack2f(b8[0], b8[1]);
      pkB.y = pack2f(b8[2], b8[3]);
      pkB.z = pack2f(b8[4], b8[5]);
      pkB.w = pack2f(b8[6], b8[7]);
      *((uint4*)&aLds[dA * AST + l16 * 4]) = pkA;
      *((uint4*)&aLds[dB * AST + l16 * 4]) = pkB;
    }
  }
  __syncthreads();

  // ---- Dual GEMM: M=32, Ncols=128, K=128, 2 phases; wave owns nt=2*wave+s ----
  const int m16 = lane & 15;
  const int quad = lane >> 4;
  const f32x4 zero4 = {0.f, 0.f, 0.f, 0.f};
  const bf16x8 zero8 = {};
  f32x4 acc[2][2];
#pragma unroll
  for (int mt = 0; mt < 2; ++mt)
#pragma unroll
    for (int s = 0; s < 2; ++s) acc[mt][s] = zero4;

#pragma unroll
  for (int ph = 0; ph < 2; ++ph) {
    const __bf16* __restrict__ W = wb + (size_t)ph * F * F;
#pragma unroll
    for (int k0 = 0; k0 < F; k0 += 32) {
      const int kcol = k0 + 8 * quad;
      bf16x8 a[2], bw[2];
#pragma unroll
      for (int mt = 0; mt < 2; ++mt) {
        if (ph == 0) {
          a[mt] = *(const bf16x8*)&aLds[(mt * 16 + m16) * AST + (kcol >> 1)];
        } else {
          int row = nodeBase + mt * 16 + m16;
          a[mt] = (row < N)
                      ? *(const bf16x8*)((const __bf16*)xb + (size_t)row * F + kcol)
                      : zero8;
        }
      }
#pragma unroll
      for (int s = 0; s < 2; ++s) {
        int nt = wave * 2 + s;
        bw[s] = *(const bf16x8*)(W + (size_t)(nt * 16 + m16) * F + kcol);
      }
#pragma unroll
      for (int mt = 0; mt < 2; ++mt)
#pragma unroll
        for (int s = 0; s < 2; ++s)
          acc[mt][s] = __builtin_amdgcn_mfma_f32_16x16x32_bf16(
              a[mt], bw[s], acc[mt][s], 0, 0, 0);
    }
  }

#pragma unroll
  for (int s = 0; s < 2; ++s) {
    int nt = wave * 2 + s;
    float bias = brel[nt * 16 + m16];
#pragma unroll
    for (int mt = 0; mt < 2; ++mt) {
      int row0 = nodeBase + mt * 16 + quad * 4;
#pragma unroll
      for (int r = 0; r < 4; ++r) {
        int row = row0 + r;
        if (row < N)
          out[(size_t)row * F + nt * 16 + m16] = fmaxf(acc[mt][s][r] + bias, 0.f);
      }
    }
  }
}

// ===========================================================================
// Fallback (tiny ws): fp32 atomics into out + fused fp32 GEMM in-place
// ===========================================================================
__global__ __launch_bounds__(256) void scatter_add_kernel(
    const float4* __restrict__ x4, const int* __restrict__ ei,
    float* __restrict__ agg, int E) {
  int gid = blockIdx.x * blockDim.x + threadIdx.x;
  if (gid >= E * 32) return;
  int e = gid >> 5, q = gid & 31;
  float4 v = x4[(size_t)ei[e] * 32 + q];
  float* a = agg + (size_t)ei[E + e] * F + q * 4;
  atomicAdd(a + 0, v.x);
  atomicAdd(a + 1, v.y);
  atomicAdd(a + 2, v.z);
  atomicAdd(a + 3, v.w);
}

#define ROWS_PER_BLOCK 64
#define SA_STRIDE 36
#define SW_STRIDE 132

__global__ __launch_bounds__(256) void gemm_fused_kernel(
    const float* __restrict__ agg, const float* __restrict__ x,
    const float* __restrict__ Wrel, const float* __restrict__ Wroot,
    const float* __restrict__ brel, float* __restrict__ out, int N) {
  __shared__ float sA[ROWS_PER_BLOCK * SA_STRIDE];
  __shared__ float sW[32 * SW_STRIDE];
  const int tid = threadIdx.x;
  const int j0 = (tid & 31) * 4;
  const int r0 = (tid >> 5) * 8;
  const int rowBase = blockIdx.x * ROWS_PER_BLOCK;
  float acc[8][4];
#pragma unroll
  for (int r = 0; r < 8; ++r)
#pragma unroll
    for (int c = 0; c < 4; ++c) acc[r][c] = 0.0f;
  for (int phase = 0; phase < 2; ++phase) {
    const float* __restrict__ A = phase ? x : agg;
    const float* __restrict__ W = phase ? Wroot : Wrel;
    for (int kc = 0; kc < F; kc += 32) {
#pragma unroll
      for (int idx = tid; idx < 512; idx += 256) {
        int row = idx >> 3, k4 = idx & 7;
        float4 v = make_float4(0.f, 0.f, 0.f, 0.f);
        int grow = rowBase + row;
        if (grow < N) v = *(const float4*)&A[(size_t)grow * F + kc + k4 * 4];
        *(float4*)&sA[row * SA_STRIDE + k4 * 4] = v;
      }
#pragma unroll
      for (int idx = tid; idx < 4096; idx += 256) {
        int j = idx >> 5, kk = idx & 31;
        sW[kk * SW_STRIDE + j] = W[j * F + kc + kk];
      }
      __syncthreads();
#pragma unroll
      for (int kk = 0; kk < 32; ++kk) {
        float4 w = *(const float4*)&sW[kk * SW_STRIDE + j0];
#pragma unroll
        for (int r = 0; r < 8; ++r) {
          float a = sA[(r0 + r) * SA_STRIDE + kk];
          acc[r][0] = fmaf(a, w.x, acc[r][0]);
          acc[r][1] = fmaf(a, w.y, acc[r][1]);
          acc[r][2] = fmaf(a, w.z, acc[r][2]);
          acc[r][3] = fmaf(a, w.w, acc[r][3]);
        }
      }
      __syncthreads();
    }
  }
  float b0 = brel[j0], b1 = brel[j0 + 1], b2 = brel[j0 + 2], b3 = brel[j0 + 3];
#pragma unroll
  for (int r = 0; r < 8; ++r) {
    int row = rowBase + r0 + r;
    if (row < N) {
      float4 v;
      v.x = fmaxf(acc[r][0] + b0, 0.0f);
      v.y = fmaxf(acc[r][1] + b1, 0.0f);
      v.z = fmaxf(acc[r][2] + b2, 0.0f);
      v.w = fmaxf(acc[r][3] + b3, 0.0f);
      *(float4*)&out[(size_t)row * F + j0] = v;
    }
  }
}

extern "C" void kernel_launch(void* const* d_in, const int* in_sizes, int n_in,
                              void* d_out, int out_size, void* d_ws, size_t ws_size,
                              hipStream_t stream) {
  const float* x     = (const float*)d_in[0];
  const int*   ei    = (const int*)d_in[1];
  const float* Wrel  = (const float*)d_in[2];
  const float* brel  = (const float*)d_in[3];
  const float* Wroot = (const float*)d_in[4];
  float* out = (float*)d_out;

  const int N = in_sizes[0] / F;       // 50000
  const int E = in_sizes[1] / 2;       // 800000
  const int NB = (N + NPB - 1) / NPB;  // 1563 buckets

  size_t xbBytes  = ((size_t)N * F * 2 + 255) & ~(size_t)255;
  size_t wBytes   = ((size_t)2 * F * F * 2 + 255) & ~(size_t)255;
  size_t curBytes = ((size_t)NPARTS * NB * sizeof(int) + 255) & ~(size_t)255;
  size_t binBytes = ((size_t)NPARTS * NB * CAP * sizeof(unsigned) + 255) & ~(size_t)255;
  size_t needBin  = curBytes + binBytes + xbBytes + wBytes;

  if (ws_size >= needBin) {
    int*      binCursor = (int*)d_ws;
    unsigned* bin = (unsigned*)((char*)d_ws + curBytes);
    unsigned* xb  = (unsigned*)((char*)d_ws + curBytes + binBytes);
    unsigned* wb  = (unsigned*)((char*)d_ws + curBytes + binBytes + xbBytes);

    int n4x = N * (F / 4);
    int n2w = F * F / 2;

    hipMemsetAsync(binCursor, 0, (size_t)NPARTS * NB * sizeof(int), stream);
    prep_bin2_kernel<<<2048, 256, 0, stream>>>(
        (const float4*)x, (const float2*)Wrel, (const float2*)Wroot, ei,
        (uint2*)xb, wb, binCursor, bin, E, NB, n4x, n2w);
    agg_gemm3_kernel<<<NB, 256, 0, stream>>>(xb, bin, binCursor,
                                             (const __bf16*)wb, brel, out, N, NB);
  } else {
    hipMemsetAsync(out, 0, (size_t)N * F * sizeof(float), stream);
    long long total = (long long)E * 32;
    scatter_add_kernel<<<(int)((total + 255) / 256), 256, 0, stream>>>(
        (const float4*)x, ei, out, E);
    gemm_fused_kernel<<<(N + ROWS_PER_BLOCK - 1) / ROWS_PER_BLOCK, 256, 0,
                        stream>>>(out, x, Wrel, Wroot, brel, out, N);
  }
}

// Round 4
// 168.052 us; speedup vs baseline: 1.0931x; 1.0931x over previous
//
#include <hip/hip_runtime.h>
#include <hip/hip_bf16.h>

// GraphConv: out = relu( segment_sum(x[src], dst) @ W_rel^T + b_rel + x @ W_root^T )
// N = 50000, F = 128, E = 800000.
//
// R15: consolidation. R14's two changes both regressed (49.6->61.4us):
//   - partOff[] runtime indexing -> scratch spill (rule: dyn-indexed local
//     arrays go to local memory), occ 50->42%
//   - paired-dst merged while-loop -> divergent short loop at mean degree 16
// => agg reverted EXACTLY to the proven agg_gemm2 (R13, 49.6us profiled).
// One safe change kept: prep_bin edge-pairing (e, e+E/2) per thread ->
// 4 independent loads + 2 overlapping atomic chains instead of 1.5 serial
// atomic round-trips per thread.
// Fallback (tiny ws): fp32 atomic scatter + fused fp32 GEMM.

#define F 128
#define NPB 32              // nodes per bucket
#define NPARTS 8            // write partitions (blockIdx%8 ~ XCD heuristic)
#define CAP 128             // slots per (part,bucket); mean 64 -> +8 sigma
#define CAPB 768            // LDS edge slots per bucket; mean 512 -> +11 sigma
#define AST 68              // A-tile row stride in uints

typedef __bf16 bf16x8 __attribute__((ext_vector_type(8)));
typedef float f32x4 __attribute__((ext_vector_type(4)));

__device__ inline unsigned f32_to_bf16_rne(float f) {
  unsigned u = __float_as_uint(f);
  unsigned r = u + 0x7fffu + ((u >> 16) & 1u);
  return r >> 16;
}
__device__ inline unsigned pack2(float2 v) {
  return f32_to_bf16_rne(v.x) | (f32_to_bf16_rne(v.y) << 16);
}
__device__ inline unsigned pack2f(float a, float b) {
  return f32_to_bf16_rne(a) | (f32_to_bf16_rne(b) << 16);
}
__device__ inline void upk4(uint4 v, float* a) {
  a[0] += __uint_as_float(v.x << 16);
  a[1] += __uint_as_float(v.x & 0xffff0000u);
  a[2] += __uint_as_float(v.y << 16);
  a[3] += __uint_as_float(v.y & 0xffff0000u);
  a[4] += __uint_as_float(v.z << 16);
  a[5] += __uint_as_float(v.z & 0xffff0000u);
  a[6] += __uint_as_float(v.w << 16);
  a[7] += __uint_as_float(v.w & 0xffff0000u);
}

// ---------------------------------------------------------------------------
// Dispatch 1: bf16 converts + edge binning (binCursor pre-zeroed by memset)
// ---------------------------------------------------------------------------
__global__ __launch_bounds__(256) void prep_bin2_kernel(
    const float4* __restrict__ x, const float2* __restrict__ w0,
    const float2* __restrict__ w1, const int* __restrict__ ei,
    uint2* __restrict__ xb2, unsigned* __restrict__ wb,
    int* __restrict__ binCursor, unsigned* __restrict__ bin,
    int E, int NB, int n4x, int n2w) {
  const int tid0 = blockIdx.x * 256 + threadIdx.x;
  const int stride = gridDim.x * 256;

  // edges first: atomics have the longest latency chains, start them early.
  // Pair (e, e+E/2): 4 independent loads in flight, 2 overlapping atomic
  // chains per iteration instead of serial per-edge round-trips.
  const int part = blockIdx.x & (NPARTS - 1);
  const int Eh = E >> 1;
  for (int e = tid0; e < Eh; e += stride) {
    unsigned s0 = (unsigned)ei[e];
    unsigned d0 = (unsigned)ei[E + e];
    unsigned s1 = (unsigned)ei[Eh + e];
    unsigned d1 = (unsigned)ei[E + Eh + e];
    int c0 = part * NB + (int)(d0 >> 5);
    int c1 = part * NB + (int)(d1 >> 5);
    int sl0 = atomicAdd(&binCursor[c0], 1);
    int sl1 = atomicAdd(&binCursor[c1], 1);
    if (sl0 < CAP) bin[(size_t)c0 * CAP + sl0] = (d0 << 16) | s0;
    if (sl1 < CAP) bin[(size_t)c1 * CAP + sl1] = (d1 << 16) | s1;
  }
  if ((E & 1) && tid0 == 0) {  // odd-E tail (not hit for E=800000)
    unsigned s = (unsigned)ei[E - 1];
    unsigned d = (unsigned)ei[2 * E - 1];
    int c = part * NB + (int)(d >> 5);
    int sl = atomicAdd(&binCursor[c], 1);
    if (sl < CAP) bin[(size_t)c * CAP + sl] = (d << 16) | s;
  }
  // x convert: float4 -> 2x packed bf16 (16B in / 8B out per iter)
  for (int i = tid0; i < n4x; i += stride) {
    float4 v = x[i];
    xb2[i] = make_uint2(pack2f(v.x, v.y), pack2f(v.z, v.w));
  }
  // weights
  for (int i = tid0; i < 2 * n2w; i += stride)
    wb[i] = (i < n2w) ? pack2(w0[i]) : pack2(w1[i - n2w]);
}

// ---------------------------------------------------------------------------
// Dispatch 2: per-bucket LDS sort + wide gather + fused dual MFMA GEMM
// (exact R13 agg_gemm2 -- proven 49.6us profiled)
// ---------------------------------------------------------------------------
__global__ __launch_bounds__(256) void agg_gemm2_kernel(
    const unsigned* __restrict__ xb, const unsigned* __restrict__ bin,
    const int* __restrict__ binCursor, const __bf16* __restrict__ wb,
    const float* __restrict__ brel, float* __restrict__ out, int N, int NB) {
  __shared__ int cntS[NPB];
  __shared__ int offS[NPB];
  __shared__ int curS[NPB];
  __shared__ unsigned short eLds[CAPB];
  __shared__ unsigned aLds[NPB * AST];

  const int b = blockIdx.x;
  const int t = threadIdx.x;
  if (t < NPB) cntS[t] = 0;
  __syncthreads();

  // stage: issue ALL partition bin-reads first (independent), then histogram
  unsigned kreg[NPARTS];
  int cnt_p[NPARTS];
#pragma unroll
  for (int p = 0; p < NPARTS; ++p) {
    int cell = p * NB + b;
    int c = min(binCursor[cell], CAP);
    cnt_p[p] = c;
    kreg[p] = (t < c) ? bin[(size_t)cell * CAP + t] : 0u;
  }
#pragma unroll
  for (int p = 0; p < NPARTS; ++p) {
    if (t < cnt_p[p]) atomicAdd(&cntS[(kreg[p] >> 16) & (NPB - 1)], 1);
  }
  __syncthreads();

  if (t < 64) {
    int v = (t < NPB) ? cntS[t] : 0;
    int incl = v;
#pragma unroll
    for (int off = 1; off < NPB; off <<= 1) {
      int u = __shfl_up(incl, off);
      if (t >= off) incl += u;
    }
    if (t < NPB) {
      offS[t] = incl - v;
      curS[t] = incl - v;
    }
  }
  __syncthreads();

#pragma unroll
  for (int p = 0; p < NPARTS; ++p) {
    if (t < cnt_p[p]) {
      int d = (kreg[p] >> 16) & (NPB - 1);
      int pos = atomicAdd(&curS[d], 1);
      if (pos < CAPB) eLds[pos] = (unsigned short)(kreg[p] & 0xffffu);
    }
  }
  __syncthreads();

  // Wide gather: 16 lanes per row, 4 rows per wave-instruction, 16B/lane.
  // Lane (grp, l16) accumulates features 8*l16 .. 8*l16+7 of row-group grp;
  // cross-group sum via shfl_xor(16) + shfl_xor(32).
  const int wave = t >> 6;
  const int lane = t & 63;
  const int grp = lane >> 4;
  const int l16 = lane & 15;
  const uint4* __restrict__ xb4 = (const uint4*)xb;
  const int nodeBase = b * NPB;
  for (int di = wave; di < NPB; di += 4) {
    float a8[8] = {0.f, 0.f, 0.f, 0.f, 0.f, 0.f, 0.f, 0.f};
    int beg = min(offS[di], CAPB);
    int end = min(offS[di] + cntS[di], CAPB);
    int e = beg;
    for (; e + 16 <= end; e += 16) {          // 16 rows: 4 x 1KB in flight
      int s0 = eLds[e + grp];
      int s1 = eLds[e + 4 + grp];
      int s2 = eLds[e + 8 + grp];
      int s3 = eLds[e + 12 + grp];
      uint4 v0 = xb4[(size_t)s0 * 16 + l16];
      uint4 v1 = xb4[(size_t)s1 * 16 + l16];
      uint4 v2 = xb4[(size_t)s2 * 16 + l16];
      uint4 v3 = xb4[(size_t)s3 * 16 + l16];
      upk4(v0, a8);
      upk4(v1, a8);
      upk4(v2, a8);
      upk4(v3, a8);
    }
    if (e + 8 <= end) {                       // 8 rows unmasked
      int s0 = eLds[e + grp];
      int s1 = eLds[e + 4 + grp];
      uint4 v0 = xb4[(size_t)s0 * 16 + l16];
      uint4 v1 = xb4[(size_t)s1 * 16 + l16];
      upk4(v0, a8);
      upk4(v1, a8);
      e += 8;
    }
    if (e < end) {                            // masked tail, up to 8 rows
      int i0 = e + grp;
      int i1 = e + 4 + grp;
      if (i0 < end) {
        uint4 v0 = xb4[(size_t)eLds[i0] * 16 + l16];
        upk4(v0, a8);
      }
      if (i1 < end) {
        uint4 v1 = xb4[(size_t)eLds[i1] * 16 + l16];
        upk4(v1, a8);
      }
    }
#pragma unroll
    for (int j = 0; j < 8; ++j) {
      a8[j] += __shfl_xor(a8[j], 16);
      a8[j] += __shfl_xor(a8[j], 32);
    }
    if (grp == 0) {
      uint4 pk;
      pk.x = pack2f(a8[0], a8[1]);
      pk.y = pack2f(a8[2], a8[3]);
      pk.z = pack2f(a8[4], a8[5]);
      pk.w = pack2f(a8[6], a8[7]);
      *((uint4*)&aLds[di * AST + l16 * 4]) = pk;
    }
  }
  __syncthreads();

  // Dual GEMM: M=32, Ncols=128, K=128, 2 phases; wave owns nt = 2*wave+s.
  const int m16 = lane & 15;
  const int quad = lane >> 4;
  const f32x4 zero4 = {0.f, 0.f, 0.f, 0.f};
  const bf16x8 zero8 = {};
  f32x4 acc[2][2];
#pragma unroll
  for (int mt = 0; mt < 2; ++mt)
#pragma unroll
    for (int s = 0; s < 2; ++s) acc[mt][s] = zero4;

#pragma unroll
  for (int ph = 0; ph < 2; ++ph) {
    const __bf16* __restrict__ W = wb + (size_t)ph * F * F;
#pragma unroll
    for (int k0 = 0; k0 < F; k0 += 32) {
      const int kcol = k0 + 8 * quad;
      bf16x8 a[2], bw[2];
#pragma unroll
      for (int mt = 0; mt < 2; ++mt) {
        if (ph == 0) {
          a[mt] = *(const bf16x8*)&aLds[(mt * 16 + m16) * AST + (kcol >> 1)];
        } else {
          int row = nodeBase + mt * 16 + m16;
          a[mt] = (row < N)
                      ? *(const bf16x8*)((const __bf16*)xb + (size_t)row * F + kcol)
                      : zero8;
        }
      }
#pragma unroll
      for (int s = 0; s < 2; ++s) {
        int nt = wave * 2 + s;
        bw[s] = *(const bf16x8*)(W + (size_t)(nt * 16 + m16) * F + kcol);
      }
#pragma unroll
      for (int mt = 0; mt < 2; ++mt)
#pragma unroll
        for (int s = 0; s < 2; ++s)
          acc[mt][s] = __builtin_amdgcn_mfma_f32_16x16x32_bf16(
              a[mt], bw[s], acc[mt][s], 0, 0, 0);
    }
  }

#pragma unroll
  for (int s = 0; s < 2; ++s) {
    int nt = wave * 2 + s;
    float bias = brel[nt * 16 + m16];
#pragma unroll
    for (int mt = 0; mt < 2; ++mt) {
      int row0 = nodeBase + mt * 16 + quad * 4;
#pragma unroll
      for (int r = 0; r < 4; ++r) {
        int row = row0 + r;
        if (row < N)
          out[(size_t)row * F + nt * 16 + m16] = fmaxf(acc[mt][s][r] + bias, 0.f);
      }
    }
  }
}

// ===========================================================================
// Fallback (tiny ws): fp32 atomics into out + fused fp32 GEMM in-place
// ===========================================================================
__global__ __launch_bounds__(256) void scatter_add_kernel(
    const float4* __restrict__ x4, const int* __restrict__ ei,
    float* __restrict__ agg, int E) {
  int gid = blockIdx.x * blockDim.x + threadIdx.x;
  if (gid >= E * 32) return;
  int e = gid >> 5, q = gid & 31;
  float4 v = x4[(size_t)ei[e] * 32 + q];
  float* a = agg + (size_t)ei[E + e] * F + q * 4;
  atomicAdd(a + 0, v.x);
  atomicAdd(a + 1, v.y);
  atomicAdd(a + 2, v.z);
  atomicAdd(a + 3, v.w);
}

#define ROWS_PER_BLOCK 64
#define SA_STRIDE 36
#define SW_STRIDE 132

__global__ __launch_bounds__(256) void gemm_fused_kernel(
    const float* __restrict__ agg, const float* __restrict__ x,
    const float* __restrict__ Wrel, const float* __restrict__ Wroot,
    const float* __restrict__ brel, float* __restrict__ out, int N) {
  __shared__ float sA[ROWS_PER_BLOCK * SA_STRIDE];
  __shared__ float sW[32 * SW_STRIDE];
  const int tid = threadIdx.x;
  const int j0 = (tid & 31) * 4;
  const int r0 = (tid >> 5) * 8;
  const int rowBase = blockIdx.x * ROWS_PER_BLOCK;
  float acc[8][4];
#pragma unroll
  for (int r = 0; r < 8; ++r)
#pragma unroll
    for (int c = 0; c < 4; ++c) acc[r][c] = 0.0f;
  for (int phase = 0; phase < 2; ++phase) {
    const float* __restrict__ A = phase ? x : agg;
    const float* __restrict__ W = phase ? Wroot : Wrel;
    for (int kc = 0; kc < F; kc += 32) {
#pragma unroll
      for (int idx = tid; idx < 512; idx += 256) {
        int row = idx >> 3, k4 = idx & 7;
        float4 v = make_float4(0.f, 0.f, 0.f, 0.f);
        int grow = rowBase + row;
        if (grow < N) v = *(const float4*)&A[(size_t)grow * F + kc + k4 * 4];
        *(float4*)&sA[row * SA_STRIDE + k4 * 4] = v;
      }
#pragma unroll
      for (int idx = tid; idx < 4096; idx += 256) {
        int j = idx >> 5, kk = idx & 31;
        sW[kk * SW_STRIDE + j] = W[j * F + kc + kk];
      }
      __syncthreads();
#pragma unroll
      for (int kk = 0; kk < 32; ++kk) {
        float4 w = *(const float4*)&sW[kk * SW_STRIDE + j0];
#pragma unroll
        for (int r = 0; r < 8; ++r) {
          float a = sA[(r0 + r) * SA_STRIDE + kk];
          acc[r][0] = fmaf(a, w.x, acc[r][0]);
          acc[r][1] = fmaf(a, w.y, acc[r][1]);
          acc[r][2] = fmaf(a, w.z, acc[r][2]);
          acc[r][3] = fmaf(a, w.w, acc[r][3]);
        }
      }
      __syncthreads();
    }
  }
  float b0 = brel[j0], b1 = brel[j0 + 1], b2 = brel[j0 + 2], b3 = brel[j0 + 3];
#pragma unroll
  for (int r = 0; r < 8; ++r) {
    int row = rowBase + r0 + r;
    if (row < N) {
      float4 v;
      v.x = fmaxf(acc[r][0] + b0, 0.0f);
      v.y = fmaxf(acc[r][1] + b1, 0.0f);
      v.z = fmaxf(acc[r][2] + b2, 0.0f);
      v.w = fmaxf(acc[r][3] + b3, 0.0f);
      *(float4*)&out[(size_t)row * F + j0] = v;
    }
  }
}

extern "C" void kernel_launch(void* const* d_in, const int* in_sizes, int n_in,
                              void* d_out, int out_size, void* d_ws, size_t ws_size,
                              hipStream_t stream) {
  const float* x     = (const float*)d_in[0];
  const int*   ei    = (const int*)d_in[1];
  const float* Wrel  = (const float*)d_in[2];
  const float* brel  = (const float*)d_in[3];
  const float* Wroot = (const float*)d_in[4];
  float* out = (float*)d_out;

  const int N = in_sizes[0] / F;       // 50000
  const int E = in_sizes[1] / 2;       // 800000
  const int NB = (N + NPB - 1) / NPB;  // 1563 buckets

  size_t xbBytes  = ((size_t)N * F * 2 + 255) & ~(size_t)255;
  size_t wBytes   = ((size_t)2 * F * F * 2 + 255) & ~(size_t)255;
  size_t curBytes = ((size_t)NPARTS * NB * sizeof(int) + 255) & ~(size_t)255;
  size_t binBytes = ((size_t)NPARTS * NB * CAP * sizeof(unsigned) + 255) & ~(size_t)255;
  size_t needBin  = curBytes + binBytes + xbBytes + wBytes;

  if (ws_size >= needBin) {
    int*      binCursor = (int*)d_ws;
    unsigned* bin = (unsigned*)((char*)d_ws + curBytes);
    unsigned* xb  = (unsigned*)((char*)d_ws + curBytes + binBytes);
    unsigned* wb  = (unsigned*)((char*)d_ws + curBytes + binBytes + xbBytes);

    int n4x = N * (F / 4);
    int n2w = F * F / 2;

    hipMemsetAsync(binCursor, 0, (size_t)NPARTS * NB * sizeof(int), stream);
    prep_bin2_kernel<<<2048, 256, 0, stream>>>(
        (const float4*)x, (const float2*)Wrel, (const float2*)Wroot, ei,
        (uint2*)xb, wb, binCursor, bin, E, NB, n4x, n2w);
    agg_gemm2_kernel<<<NB, 256, 0, stream>>>(xb, bin, binCursor,
                                             (const __bf16*)wb, brel, out, N, NB);
  } else {
    hipMemsetAsync(out, 0, (size_t)N * F * sizeof(float), stream);
    long long total = (long long)E * 32;
    scatter_add_kernel<<<(int)((total + 255) / 256), 256, 0, stream>>>(
        (const float4*)x, ei, out, E);
    gemm_fused_kernel<<<(N + ROWS_PER_BLOCK - 1) / ROWS_PER_BLOCK, 256, 0,
                        stream>>>(out, x, Wrel, Wroot, brel, out, N);
  }
}